// Round 18
// baseline (283.143 us; speedup 1.0000x reference)
//
#include <hip/hip_runtime.h>
#include <hip/hip_bf16.h>

// PSN: quantize latents (16384 x 256) f32 against codebook (8192 x 256) f32.
// Outputs (flat f32): st[16384*256], loss[1], inds_noisy[16384] (as float).
//
// Pipeline: prep(split f32 -> bf16 hi/lo, X frag-major) -> prepw(split+wnorm)
// -> pass1 MFMA argmin w/ top-2 (3-buffer LDS ring, FIFO-ordered issue,
// counted vmcnt(8) + raw barrier: stages stay in flight across barriers) ->
// flag -> rerank -> finalize.

namespace {
constexpr int N_ROWS  = 16384;
constexpr int K_CODES = 8192;
constexpr int C_DIM   = 256;
constexpr float EPS_GAP = 0.004f;   // ~4x the bf16-split score-error tail
}

typedef __attribute__((ext_vector_type(8)))  short bf16x8;
typedef __attribute__((ext_vector_type(16))) float f32x16;

typedef __attribute__((address_space(1))) const unsigned int gas_u32;
typedef __attribute__((address_space(3))) unsigned int las_u32;

__device__ __forceinline__ void gld16(const unsigned short* g, unsigned short* l) {
    __builtin_amdgcn_global_load_lds((gas_u32*)g, (las_u32*)l, 16, 0, 0);
}

__device__ __forceinline__ unsigned f2key(float f) {
    unsigned u = __float_as_uint(f);
    return (u & 0x80000000u) ? ~u : (u | 0x80000000u);
}
__device__ __forceinline__ float key2f(unsigned k) {
    unsigned u = (k & 0x80000000u) ? (k ^ 0x80000000u) : ~k;
    return __uint_as_float(u);
}
__device__ __forceinline__ unsigned short f2bf(float x) {
    unsigned u = __float_as_uint(x);
    unsigned r = u + 0x7fffu + ((u >> 16) & 1u);   // RNE
    return (unsigned short)(r >> 16);
}

// ---------------- prep latents: f32 -> bf16 hi/lo, FRAGMENT-MAJOR ----------
extern "C" __global__ void prep_kernel(const float* __restrict__ src,
                                       unsigned short* __restrict__ hi,
                                       unsigned short* __restrict__ lo) {
    const int i = (blockIdx.x * 256 + threadIdx.x) * 8;
    const int row = i >> 8, col = i & 255;
    const int d = (((row >> 5) * 8 + (col >> 5)) * 4 + ((col >> 3) & 3)) * 256
                + (row & 31) * 8;
    float4 a = *(const float4*)&src[i];
    float4 b = *(const float4*)&src[i + 4];
    float v[8] = {a.x, a.y, a.z, a.w, b.x, b.y, b.z, b.w};
    unsigned short h[8], l[8];
    #pragma unroll
    for (int j = 0; j < 8; ++j) {
        h[j] = f2bf(v[j]);
        float hf = __uint_as_float((unsigned)h[j] << 16);
        l[j] = f2bf(v[j] - hf);
    }
    ushort4 h0 = {h[0], h[1], h[2], h[3]}, h1 = {h[4], h[5], h[6], h[7]};
    ushort4 l0 = {l[0], l[1], l[2], l[3]}, l1 = {l[4], l[5], l[6], l[7]};
    *(ushort4*)&hi[d] = h0;  *(ushort4*)&hi[d + 4] = h1;
    *(ushort4*)&lo[d] = l0;  *(ushort4*)&lo[d + 4] = l1;
}

// ---------------- prep codebook: split + fused wnorm (row-major) ----------
extern "C" __global__ void prepw_kernel(const float* __restrict__ src,
                                        unsigned short* __restrict__ hi,
                                        unsigned short* __restrict__ lo,
                                        float* __restrict__ wnorm) {
    const int i = (blockIdx.x * 256 + threadIdx.x) * 8;
    float4 a = *(const float4*)&src[i];
    float4 b = *(const float4*)&src[i + 4];
    float v[8] = {a.x, a.y, a.z, a.w, b.x, b.y, b.z, b.w};
    unsigned short h[8], l[8];
    float s = 0.0f;
    #pragma unroll
    for (int j = 0; j < 8; ++j) {
        h[j] = f2bf(v[j]);
        float hf = __uint_as_float((unsigned)h[j] << 16);
        l[j] = f2bf(v[j] - hf);
        s = fmaf(v[j], v[j], s);
    }
    ushort4 h0 = {h[0], h[1], h[2], h[3]}, h1 = {h[4], h[5], h[6], h[7]};
    ushort4 l0 = {l[0], l[1], l[2], l[3]}, l1 = {l[4], l[5], l[6], l[7]};
    *(ushort4*)&hi[i] = h0;  *(ushort4*)&hi[i + 4] = h1;
    *(ushort4*)&lo[i] = l0;  *(ushort4*)&lo[i + 4] = l1;
    #pragma unroll
    for (int m = 1; m < 32; m <<= 1) s += __shfl_xor(s, m, 64);
    if ((threadIdx.x & 31) == 0) wnorm[i >> 8] = s;
}

// ---------------- pass1: MFMA approx argmin, top-2 per row ----------------
// grid 2048: rb = bid&127, cs = bid>>7 (512 codes/block, 32 tiles). Wave
// tile 32 rows x 128 codes, 48-reg carry, 3 waves/SIMD.
// PIPELINE (r17 post-mortem; fixes r12's FIFO-order bug): 3-buffer LDS ring
// (48KB <= 53KB for 3 blocks/CU); per tile issue order PINNED as
// [wn?] -> LOADA(t+1) -> stageW(t+2); tile ends with vmcnt(8)+s_barrier,
// draining exactly stage(t+1) (each wave its own portion -> after barrier
// all portions landed) while A(t+1)+stage(t+2) stay in flight. Edge tiles
// issue harmless in-bounds garbage loads so the static ledger is exact.
extern "C" __global__ void __launch_bounds__(256, 3)
pass1_kernel(const unsigned short* __restrict__ xh_g,
             const unsigned short* __restrict__ xl_g,
             const unsigned short* __restrict__ wh_g,
             const unsigned short* __restrict__ wl_g,
             const float* __restrict__ wnorm,
             unsigned long long* __restrict__ keys,
             unsigned* __restrict__ keys2) {
    __shared__ __align__(16) unsigned short LDS[3][2][128 * 32];   // 48KB ring
    const int tid = threadIdx.x;
    const int lane = tid & 63;
    const int wid = tid >> 6;            // wave owns rows wid*32..wid*32+31
    const int h = lane >> 5;
    const int l31 = lane & 31;
    const int rb = blockIdx.x & 127, cs = blockIdx.x >> 7;
    const int r0 = rb * 128, cbase = cs * 512;

    // W staging: pre-swizzled global quarter, LDS dest linear
    const int dr = lane >> 2;
    const int gq = (lane & 3) ^ ((lane >> 3) & 3);
    const int laneoff = dr * 256 + gq * 8;

    // B fragment: group g row = g*32 + l31; swizzle phase group-invariant
    const int fB = (l31 >> 1) & 3;

    // A frag-major base (row group rb*4 + wid)
    const size_t abase = ((size_t)(rb * 4 + wid) * 8) * 1024 + h * 256 + l31 * 8;

    // carried top-2 state: 16 row-slots (48 regs)
    float bv[16];  unsigned bi[16];  float sv[16];
    #pragma unroll
    for (int r = 0; r < 16; ++r) { bv[r] = 3.4e38f; sv[r] = 3.4e38f; bi[r] = 0; }

    f32x16 acc[4];                       // one per 32-code column group
    #pragma unroll
    for (int g = 0; g < 4; ++g)
        #pragma unroll
        for (int e = 0; e < 16; ++e) acc[g][e] = 0.0f;

    auto stageW = [&](int t) {           // 4 vmcnt events; buf = t%3
        const int b = t % 3;
        const int kc32 = (t & 7) * 32;
        const int cb = cbase + (t >> 3) * 128;
        #pragma unroll
        for (int c = 0; c < 2; ++c) {
            const int R = wid * 32 + c * 16;
            const size_t wg = (size_t)(cb + R) * 256 + kc32 + laneoff;
            gld16(wh_g + wg, &LDS[b][0][R * 32]);
            gld16(wl_g + wg, &LDS[b][1][R * 32]);
        }
    };

    // two named A sets (double-buffer); per-panel wnorm regs
    bf16x8 cAh0, cAh1, cAl0, cAl1;
    bf16x8 nAh0, nAh1, nAl0, nAl1;
    float wn0 = 0, wn1 = 0, wn2 = 0, wn3 = 0;

#define SCHED() __builtin_amdgcn_sched_barrier(0)
#define WAITBAR()                                                              \
    {   asm volatile("s_waitcnt vmcnt(8)" ::: "memory");                       \
        SCHED();                                                               \
        __builtin_amdgcn_s_barrier();                                          \
        SCHED();                                                               \
    }

#define LOADA(H0, H1, L0, L1, tt)                                              \
    {   const size_t o_ = abase + (size_t)((tt) & 7) * 1024;                   \
        H0 = *(const bf16x8*)(xh_g + o_);                                      \
        H1 = *(const bf16x8*)(xh_g + o_ + 512);                                \
        L0 = *(const bf16x8*)(xl_g + o_);                                      \
        L1 = *(const bf16x8*)(xl_g + o_ + 512);                                \
    }

#define MFMA_TILE(H0, H1, L0, L1, P)                                           \
    {   _Pragma("unroll")                                                      \
        for (int kk = 0; kk < 2; ++kk) {                                       \
            const int q = kk * 2 + h;                                          \
            bf16x8 ah = kk ? H1 : H0;                                          \
            bf16x8 al = kk ? L1 : L0;                                          \
            _Pragma("unroll")                                                  \
            for (int g = 0; g < 4; ++g) {                                      \
                const int aB = (g * 32 + l31) * 32 + ((q ^ fB) << 3);          \
                bf16x8 bh = *(const bf16x8*)&LDS[P][0][aB];                    \
                bf16x8 bl = *(const bf16x8*)&LDS[P][1][aB];                    \
                acc[g] = __builtin_amdgcn_mfma_f32_32x32x16_bf16(ah, bh, acc[g], 0, 0, 0); \
                acc[g] = __builtin_amdgcn_mfma_f32_32x32x16_bf16(ah, bl, acc[g], 0, 0, 0); \
                acc[g] = __builtin_amdgcn_mfma_f32_32x32x16_bf16(al, bh, acc[g], 0, 0, 0); \
            }                                                                  \
        }                                                                      \
    }

    // epilogue: merge 4 column-group candidates into the per-row carry
    // (uses preloaded wn regs -> no memory ops in the epilogue tile)
    auto epilogue = [&](int t) {
        const int cb = cbase + (t >> 3) * 128;
        #pragma unroll
        for (int r = 0; r < 16; ++r) {
            #pragma unroll
            for (int g = 0; g < 4; ++g) {
                const float wn = g == 0 ? wn0 : g == 1 ? wn1 : g == 2 ? wn2 : wn3;
                float s = fmaf(-2.0f, acc[g][r], wn);
                bool c = s < bv[r];
                sv[r] = fminf(sv[r], c ? bv[r] : s);
                bv[r] = c ? s : bv[r];
                bi[r] = c ? (unsigned)(cb + g * 32 + l31) : bi[r];
            }
        }
        #pragma unroll
        for (int g = 0; g < 4; ++g)
            #pragma unroll
            for (int e = 0; e < 16; ++e) acc[g][e] = 0.0f;
    };

    // prologue FIFO: stage(0), A(0), stage(1); vmcnt(8) drains stage(0).
    stageW(0);
    SCHED();
    LOADA(cAh0, cAh1, cAl0, cAl1, 0);
    SCHED();
    stageW(1);
    WAITBAR();

    for (int t2 = 0; t2 < 32; t2 += 2) {
        // ---- even tile t2: buf t2%3, A set c ----
        if ((t2 & 7) == 0) {             // panel wnorm preload (issued FIRST:
            const int cb = cbase + (t2 >> 3) * 128;   // drains with stage(t+1))
            wn0 = wnorm[cb + l31];
            wn1 = wnorm[cb + 32 + l31];
            wn2 = wnorm[cb + 64 + l31];
            wn3 = wnorm[cb + 96 + l31];
        }
        SCHED();
        LOADA(nAh0, nAh1, nAl0, nAl1, t2 + 1);
        SCHED();
        stageW(t2 + 2);                  // garbage-but-valid past t=31
        SCHED();
        MFMA_TILE(cAh0, cAh1, cAl0, cAl1, t2 % 3);
        WAITBAR();                       // drains stage(t2+1)

        // ---- odd tile t2+1: buf (t2+1)%3, A set n ----
        LOADA(cAh0, cAh1, cAl0, cAl1, t2 + 2);
        SCHED();
        stageW(t2 + 3);                  // garbage-but-valid past t=31
        SCHED();
        MFMA_TILE(nAh0, nAh1, nAl0, nAl1, (t2 + 1) % 3);
        if (((t2 + 1) & 7) == 7) epilogue(t2 + 1);
        WAITBAR();                       // drains stage(t2+2)
    }
#undef LOADA
#undef MFMA_TILE
#undef WAITBAR
#undef SCHED

    // final cross-lane merge (32 code-lanes share each row set) + global top-2
    #pragma unroll
    for (int r = 0; r < 16; ++r) {
        unsigned long long key =
            ((unsigned long long)f2key(bv[r]) << 32) | bi[r];
        unsigned sk = f2key(sv[r]);
        #pragma unroll
        for (int m = 1; m < 32; m <<= 1) {
            unsigned long long ko = __shfl_xor(key, m, 64);
            unsigned sko = __shfl_xor(sk, m, 64);
            unsigned long long loser = key < ko ? ko : key;
            sk = min(min(sk, sko), (unsigned)(loser >> 32));
            key = key < ko ? key : ko;
        }
        if (l31 == 0) {
            const int grow = r0 + wid * 32 + (r & 3) + 8 * (r >> 2) + 4 * h;
            unsigned long long old = atomicMin(&keys[grow], key);
            if (old != ~0ull) {
                unsigned long long loser = old < key ? key : old;
                atomicMin(&keys2[grow], (unsigned)(loser >> 32));
            }
            atomicMin(&keys2[grow], sk);
        }
    }
}

// ---------------- flag near-ties ----------------
extern "C" __global__ void flag_kernel(unsigned long long* __restrict__ keys,
                                       const unsigned* __restrict__ keys2,
                                       int* __restrict__ list, int* __restrict__ count) {
    const int row = blockIdx.x * 256 + threadIdx.x;
    unsigned long long k = keys[row];
    float b = key2f((unsigned)(k >> 32));
    float s = key2f(keys2[row]);
    if (s - b < EPS_GAP) {
        int p = atomicAdd(count, 1);
        list[p] = row;
        keys[row] = ~0ull;   // rerank rebuilds from scratch
    }
}

// ---------------- exact f32 rerank (code-resident, read-before-atomic) -----
extern "C" __global__ void __launch_bounds__(256)
rerank_kernel(const float* __restrict__ lat,
              const float* __restrict__ cbk,
              const float* __restrict__ wnorm,
              const int* __restrict__ list,
              const int* __restrict__ count,
              unsigned long long* __restrict__ keys) {
    const int w = threadIdx.x >> 6, lane = threadIdx.x & 63;
    const int c0 = blockIdx.x * 16 + w * 4;
    float4 wv0 = *(const float4*)&cbk[(size_t)(c0 + 0) * C_DIM + lane * 4];
    float4 wv1 = *(const float4*)&cbk[(size_t)(c0 + 1) * C_DIM + lane * 4];
    float4 wv2 = *(const float4*)&cbk[(size_t)(c0 + 2) * C_DIM + lane * 4];
    float4 wv3 = *(const float4*)&cbk[(size_t)(c0 + 3) * C_DIM + lane * 4];
    const float wn0 = wnorm[c0 + 0], wn1 = wnorm[c0 + 1];
    const float wn2 = wnorm[c0 + 2], wn3 = wnorm[c0 + 3];
    const int n = *count;

    auto dot4 = [&](const float4& x, const float4& v) {
        float d = x.x * v.x;
        d = fmaf(x.y, v.y, d);
        d = fmaf(x.z, v.z, d);
        return fmaf(x.w, v.w, d);
    };
    auto best4 = [&](float a0, float a1, float a2, float a3) {
        unsigned long long k0 = ((unsigned long long)f2key(fmaf(-2.0f, a0, wn0)) << 32) | (unsigned)(c0 + 0);
        unsigned long long k1 = ((unsigned long long)f2key(fmaf(-2.0f, a1, wn1)) << 32) | (unsigned)(c0 + 1);
        unsigned long long k2 = ((unsigned long long)f2key(fmaf(-2.0f, a2, wn2)) << 32) | (unsigned)(c0 + 2);
        unsigned long long k3 = ((unsigned long long)f2key(fmaf(-2.0f, a3, wn3)) << 32) | (unsigned)(c0 + 3);
        unsigned long long b01 = k0 < k1 ? k0 : k1;
        unsigned long long b23 = k2 < k3 ? k2 : k3;
        return b01 < b23 ? b01 : b23;
    };

    int i = 0;
    for (; i + 2 <= n; i += 2) {
        const int r0 = list[i], r1 = list[i + 1];
        float4 x0 = *(const float4*)&lat[(size_t)r0 * C_DIM + lane * 4];
        float4 x1 = *(const float4*)&lat[(size_t)r1 * C_DIM + lane * 4];
        float d00 = dot4(x0, wv0), d01 = dot4(x0, wv1), d02 = dot4(x0, wv2), d03 = dot4(x0, wv3);
        float d10 = dot4(x1, wv0), d11 = dot4(x1, wv1), d12 = dot4(x1, wv2), d13 = dot4(x1, wv3);
        #pragma unroll
        for (int m = 1; m < 64; m <<= 1) {
            d00 += __shfl_xor(d00, m, 64); d01 += __shfl_xor(d01, m, 64);
            d02 += __shfl_xor(d02, m, 64); d03 += __shfl_xor(d03, m, 64);
            d10 += __shfl_xor(d10, m, 64); d11 += __shfl_xor(d11, m, 64);
            d12 += __shfl_xor(d12, m, 64); d13 += __shfl_xor(d13, m, 64);
        }
        if (lane == 0) {
            unsigned long long b0 = best4(d00, d01, d02, d03);
            unsigned long long b1 = best4(d10, d11, d12, d13);
            if (b0 < keys[r0]) atomicMin(&keys[r0], b0);
            if (b1 < keys[r1]) atomicMin(&keys[r1], b1);
        }
    }
    if (i < n) {
        const int r0 = list[i];
        float4 x0 = *(const float4*)&lat[(size_t)r0 * C_DIM + lane * 4];
        float d00 = dot4(x0, wv0), d01 = dot4(x0, wv1), d02 = dot4(x0, wv2), d03 = dot4(x0, wv3);
        #pragma unroll
        for (int m = 1; m < 64; m <<= 1) {
            d00 += __shfl_xor(d00, m, 64); d01 += __shfl_xor(d01, m, 64);
            d02 += __shfl_xor(d02, m, 64); d03 += __shfl_xor(d03, m, 64);
        }
        if (lane == 0) {
            unsigned long long b0 = best4(d00, d01, d02, d03);
            if (b0 < keys[r0]) atomicMin(&keys[r0], b0);
        }
    }
}

// ---------------- finalize: 8 rows/block (2048 blocks) ----------------
extern "C" __global__ void finalize_kernel(const float* __restrict__ lat,
                                           const float* __restrict__ cbk,
                                           const float* __restrict__ noise,
                                           const unsigned long long* __restrict__ keys,
                                           float* __restrict__ out,
                                           float* __restrict__ lpart) {
    const int g = threadIdx.x >> 5;
    const int l = threadIdx.x & 31;
    const int row = blockIdx.x * 8 + g;
    const unsigned long long p = keys[row];
    const int id = (int)(unsigned)(p & 0xFFFFFFFFull);
    const int off = (int)rintf(noise[row] * 0.5f);
    int idn = id + off;
    idn = idn < 0 ? 0 : (idn > K_CODES - 1 ? K_CODES - 1 : idn);
    const float4* latp = (const float4*)&lat[(size_t)row * C_DIM];
    const float4* qdp  = (const float4*)&cbk[(size_t)id  * C_DIM];
    const float4* qnp  = (const float4*)&cbk[(size_t)idn * C_DIM];
    float4* stp = (float4*)&out[(size_t)row * C_DIM];
    float t = 0.0f;
    #pragma unroll
    for (int j = 0; j < 2; ++j) {
        const int e = l + j * 32;
        float4 x  = latp[e];
        float4 qd = qdp[e];
        float4 qn = qnp[e];
        float4 st = {x.x + (qn.x - x.x), x.y + (qn.y - x.y),
                     x.z + (qn.z - x.z), x.w + (qn.w - x.w)};
        stp[e] = st;
        float d1, d2;
        d1 = x.x - qd.x; d2 = qn.x - x.x; t += 0.25f * d1 * d1 + d2 * d2;
        d1 = x.y - qd.y; d2 = qn.y - x.y; t += 0.25f * d1 * d1 + d2 * d2;
        d1 = x.z - qd.z; d2 = qn.z - x.z; t += 0.25f * d1 * d1 + d2 * d2;
        d1 = x.w - qd.w; d2 = qn.w - x.w; t += 0.25f * d1 * d1 + d2 * d2;
    }
    t *= (1.0f / 4194304.0f);
    #pragma unroll
    for (int m = 1; m < 32; m <<= 1) t += __shfl_xor(t, m, 64);
    __shared__ float red[8];
    if (l == 0) {
        red[g] = t;
        out[(size_t)N_ROWS * C_DIM + 1 + row] = (float)idn;
    }
    __syncthreads();
    if (threadIdx.x == 0) {
        float s = red[0] + red[1] + red[2] + red[3] + red[4] + red[5] + red[6] + red[7];
        atomicAdd(&lpart[blockIdx.x & 1023], s);
    }
}

extern "C" __global__ void loss_reduce_kernel(const float* __restrict__ lpart,
                                              float* __restrict__ out) {
    const int t = threadIdx.x;
    float s = lpart[t] + lpart[t + 256] + lpart[t + 512] + lpart[t + 768];
    #pragma unroll
    for (int m = 32; m; m >>= 1) s += __shfl_xor(s, m, 64);
    __shared__ float red[4];
    if ((t & 63) == 0) red[t >> 6] = s;
    __syncthreads();
    if (t == 0) out[(size_t)N_ROWS * C_DIM] = red[0] + red[1] + red[2] + red[3];
}

extern "C" void kernel_launch(void* const* d_in, const int* in_sizes, int n_in,
                              void* d_out, int out_size, void* d_ws, size_t ws_size,
                              hipStream_t stream) {
    const float* lat   = (const float*)d_in[0];
    const float* cbk   = (const float*)d_in[1];
    const float* noise = (const float*)d_in[2];
    float* out = (float*)d_out;

    char* ws = (char*)d_ws;
    unsigned short* xh = (unsigned short*)(ws);                      //  8 MB (frag-major)
    unsigned short* xl = (unsigned short*)(ws + 8388608);            //  8 MB (frag-major)
    unsigned short* wh = (unsigned short*)(ws + 16777216);           //  4 MB (row-major)
    unsigned short* wl = (unsigned short*)(ws + 20971520);           //  4 MB (row-major)
    float* wnorm       = (float*)(ws + 25165824);                    // 32 KB
    unsigned long long* keys = (unsigned long long*)(ws + 25198592); // 128 KB  \ one
    unsigned* keys2    = (unsigned*)(ws + 25329664);                 // 64 KB   / 0xFF memset
    int* list          = (int*)(ws + 25395200);                      // 64 KB
    float* lpart       = (float*)(ws + 25460736);                    // 4 KB    \ one
    int* count         = (int*)(ws + 25464832);                      // 4 B     / 0 memset

    hipMemsetAsync(keys, 0xFF, 192 * 1024, stream);                  // keys + keys2
    hipMemsetAsync(lpart, 0, 4096 + 4, stream);                      // lpart + count

    prep_kernel <<<2048, 256, 0, stream>>>(lat, xh, xl);
    prepw_kernel<<<1024, 256, 0, stream>>>(cbk, wh, wl, wnorm);
    pass1_kernel<<<2048, 256, 0, stream>>>(xh, xl, wh, wl, wnorm, keys, keys2);
    flag_kernel <<<N_ROWS / 256, 256, 0, stream>>>(keys, keys2, list, count);
    rerank_kernel<<<K_CODES / 16, 256, 0, stream>>>(lat, cbk, wnorm, list, count, keys);
    finalize_kernel<<<N_ROWS / 8, 256, 0, stream>>>(lat, cbk, noise, keys, out, lpart);
    loss_reduce_kernel<<<1, 256, 0, stream>>>(lpart, out);
}

// Round 19
// 272.310 us; speedup vs baseline: 1.0398x; 1.0398x over previous
//
#include <hip/hip_runtime.h>
#include <hip/hip_bf16.h>

// PSN: quantize latents (16384 x 256) f32 against codebook (8192 x 256) f32.
// Outputs (flat f32): st[16384*256], loss[1], inds_noisy[16384] (as float).
//
// Best-measured configuration (r16): pass1 with wave = 32 rows x 128 codes,
// 48-reg top-2 carry, 3 waves/SIMD, A double-buffered in regs, W in LDS
// 2-buffer via global_load_lds. prep/prepw fused into one launch.

namespace {
constexpr int N_ROWS  = 16384;
constexpr int K_CODES = 8192;
constexpr int C_DIM   = 256;
constexpr float EPS_GAP = 0.004f;   // ~4x the bf16-split score-error tail
}

typedef __attribute__((ext_vector_type(8)))  short bf16x8;
typedef __attribute__((ext_vector_type(16))) float f32x16;

typedef __attribute__((address_space(1))) const unsigned int gas_u32;
typedef __attribute__((address_space(3))) unsigned int las_u32;

__device__ __forceinline__ void gld16(const unsigned short* g, unsigned short* l) {
    __builtin_amdgcn_global_load_lds((gas_u32*)g, (las_u32*)l, 16, 0, 0);
}

__device__ __forceinline__ unsigned f2key(float f) {
    unsigned u = __float_as_uint(f);
    return (u & 0x80000000u) ? ~u : (u | 0x80000000u);
}
__device__ __forceinline__ float key2f(unsigned k) {
    unsigned u = (k & 0x80000000u) ? (k ^ 0x80000000u) : ~k;
    return __uint_as_float(u);
}
__device__ __forceinline__ unsigned short f2bf(float x) {
    unsigned u = __float_as_uint(x);
    unsigned r = u + 0x7fffu + ((u >> 16) & 1u);   // RNE
    return (unsigned short)(r >> 16);
}

// ---------------- fused prep: blocks 0..2047 = latents (frag-major),
//                  blocks 2048..3071 = codebook (row-major + wnorm) --------
extern "C" __global__ void prep_all_kernel(const float* __restrict__ lat,
                                           const float* __restrict__ cbk,
                                           unsigned short* __restrict__ xhi,
                                           unsigned short* __restrict__ xlo,
                                           unsigned short* __restrict__ whi,
                                           unsigned short* __restrict__ wlo,
                                           float* __restrict__ wnorm) {
    if (blockIdx.x < 2048) {
        const int i = (blockIdx.x * 256 + threadIdx.x) * 8;
        const int row = i >> 8, col = i & 255;
        const int d = (((row >> 5) * 8 + (col >> 5)) * 4 + ((col >> 3) & 3)) * 256
                    + (row & 31) * 8;
        float4 a = *(const float4*)&lat[i];
        float4 b = *(const float4*)&lat[i + 4];
        float v[8] = {a.x, a.y, a.z, a.w, b.x, b.y, b.z, b.w};
        unsigned short h[8], l[8];
        #pragma unroll
        for (int j = 0; j < 8; ++j) {
            h[j] = f2bf(v[j]);
            float hf = __uint_as_float((unsigned)h[j] << 16);
            l[j] = f2bf(v[j] - hf);
        }
        ushort4 h0 = {h[0], h[1], h[2], h[3]}, h1 = {h[4], h[5], h[6], h[7]};
        ushort4 l0 = {l[0], l[1], l[2], l[3]}, l1 = {l[4], l[5], l[6], l[7]};
        *(ushort4*)&xhi[d] = h0;  *(ushort4*)&xhi[d + 4] = h1;
        *(ushort4*)&xlo[d] = l0;  *(ushort4*)&xlo[d + 4] = l1;
    } else {
        const int i = ((blockIdx.x - 2048) * 256 + threadIdx.x) * 8;
        float4 a = *(const float4*)&cbk[i];
        float4 b = *(const float4*)&cbk[i + 4];
        float v[8] = {a.x, a.y, a.z, a.w, b.x, b.y, b.z, b.w};
        unsigned short h[8], l[8];
        float s = 0.0f;
        #pragma unroll
        for (int j = 0; j < 8; ++j) {
            h[j] = f2bf(v[j]);
            float hf = __uint_as_float((unsigned)h[j] << 16);
            l[j] = f2bf(v[j] - hf);
            s = fmaf(v[j], v[j], s);
        }
        ushort4 h0 = {h[0], h[1], h[2], h[3]}, h1 = {h[4], h[5], h[6], h[7]};
        ushort4 l0 = {l[0], l[1], l[2], l[3]}, l1 = {l[4], l[5], l[6], l[7]};
        *(ushort4*)&whi[i] = h0;  *(ushort4*)&whi[i + 4] = h1;
        *(ushort4*)&wlo[i] = l0;  *(ushort4*)&wlo[i + 4] = l1;
        #pragma unroll
        for (int m = 1; m < 32; m <<= 1) s += __shfl_xor(s, m, 64);
        if ((threadIdx.x & 31) == 0) wnorm[i >> 8] = s;
    }
}

// ---------------- pass1: MFMA approx argmin, top-2 per row ----------------
// grid 1024: rb = bid&127, cs = bid>>7. Wave tile 32 rows x 128 codes,
// 48-reg top-2 carry -> 3 waves/SIMD (r15); A double-buffered in regs (r16:
// +5%); W staged in LDS 2-buffer via global_load_lds, pre-swizzled source.
// This is the best-measured configuration (pass1 222us, MfmaUtil 44% = 92%
// of the 3-wave occupancy-capped limit; r6/r12/r17/r18 pipelining variants
// were all null -> 2-phase structural plateau).
extern "C" __global__ void __launch_bounds__(256, 3)
pass1_kernel(const unsigned short* __restrict__ xh_g,
             const unsigned short* __restrict__ xl_g,
             const unsigned short* __restrict__ wh_g,
             const unsigned short* __restrict__ wl_g,
             const float* __restrict__ wnorm,
             unsigned long long* __restrict__ keys,
             unsigned* __restrict__ keys2) {
    __shared__ __align__(16) unsigned short LDS[2][2][128 * 32];   // 32KB
    const int tid = threadIdx.x;
    const int lane = tid & 63;
    const int wid = tid >> 6;            // wave owns rows wid*32..wid*32+31
    const int h = lane >> 5;
    const int l31 = lane & 31;
    const int rb = blockIdx.x & 127, cs = blockIdx.x >> 7;
    const int r0 = rb * 128, cbase = cs * 1024;

    const int dr = lane >> 2;
    const int gq = (lane & 3) ^ ((lane >> 3) & 3);
    const int laneoff = dr * 256 + gq * 8;

    const int fB = (l31 >> 1) & 3;

    const size_t abase = ((size_t)(rb * 4 + wid) * 8) * 1024 + h * 256 + l31 * 8;

    float bv[16];  unsigned bi[16];  float sv[16];
    #pragma unroll
    for (int r = 0; r < 16; ++r) { bv[r] = 3.4e38f; sv[r] = 3.4e38f; bi[r] = 0; }

    f32x16 acc[4];
    #pragma unroll
    for (int g = 0; g < 4; ++g)
        #pragma unroll
        for (int e = 0; e < 16; ++e) acc[g][e] = 0.0f;

    auto stageW = [&](int t, int b) {
        const int kc32 = (t & 7) * 32;
        const int cb = cbase + (t >> 3) * 128;
        #pragma unroll
        for (int c = 0; c < 2; ++c) {
            const int R = wid * 32 + c * 16;
            const size_t wg = (size_t)(cb + R) * 256 + kc32 + laneoff;
            gld16(wh_g + wg, &LDS[b][0][R * 32]);
            gld16(wl_g + wg, &LDS[b][1][R * 32]);
        }
    };

    bf16x8 cAh0, cAh1, cAl0, cAl1;
    bf16x8 nAh0, nAh1, nAl0, nAl1;

#define LOADA(H0, H1, L0, L1, tt)                                              \
    {   const size_t o_ = abase + (size_t)((tt) & 7) * 1024;                   \
        H0 = *(const bf16x8*)(xh_g + o_);                                      \
        H1 = *(const bf16x8*)(xh_g + o_ + 512);                                \
        L0 = *(const bf16x8*)(xl_g + o_);                                      \
        L1 = *(const bf16x8*)(xl_g + o_ + 512);                                \
    }

#define MFMA_TILE(H0, H1, L0, L1, P)                                           \
    {   _Pragma("unroll")                                                      \
        for (int kk = 0; kk < 2; ++kk) {                                       \
            const int q = kk * 2 + h;                                          \
            bf16x8 ah = kk ? H1 : H0;                                          \
            bf16x8 al = kk ? L1 : L0;                                          \
            _Pragma("unroll")                                                  \
            for (int g = 0; g < 4; ++g) {                                      \
                const int aB = (g * 32 + l31) * 32 + ((q ^ fB) << 3);          \
                bf16x8 bh = *(const bf16x8*)&LDS[P][0][aB];                    \
                bf16x8 bl = *(const bf16x8*)&LDS[P][1][aB];                    \
                acc[g] = __builtin_amdgcn_mfma_f32_32x32x16_bf16(ah, bh, acc[g], 0, 0, 0); \
                acc[g] = __builtin_amdgcn_mfma_f32_32x32x16_bf16(ah, bl, acc[g], 0, 0, 0); \
                acc[g] = __builtin_amdgcn_mfma_f32_32x32x16_bf16(al, bh, acc[g], 0, 0, 0); \
            }                                                                  \
        }                                                                      \
    }

    auto epilogue = [&](int t) {
        const int cb = cbase + (t >> 3) * 128;
        float wn0 = wnorm[cb + l31];
        float wn1 = wnorm[cb + 32 + l31];
        float wn2 = wnorm[cb + 64 + l31];
        float wn3 = wnorm[cb + 96 + l31];
        #pragma unroll
        for (int r = 0; r < 16; ++r) {
            #pragma unroll
            for (int g = 0; g < 4; ++g) {
                const float wn = g == 0 ? wn0 : g == 1 ? wn1 : g == 2 ? wn2 : wn3;
                float s = fmaf(-2.0f, acc[g][r], wn);
                bool c = s < bv[r];
                sv[r] = fminf(sv[r], c ? bv[r] : s);
                bv[r] = c ? s : bv[r];
                bi[r] = c ? (unsigned)(cb + g * 32 + l31) : bi[r];
            }
        }
        #pragma unroll
        for (int g = 0; g < 4; ++g)
            #pragma unroll
            for (int e = 0; e < 16; ++e) acc[g][e] = 0.0f;
    };

    stageW(0, 0);
    LOADA(cAh0, cAh1, cAl0, cAl1, 0);
    __syncthreads();
    for (int t2 = 0; t2 < 64; t2 += 2) {
        stageW(t2 + 1, 1);
        LOADA(nAh0, nAh1, nAl0, nAl1, t2 + 1);
        MFMA_TILE(cAh0, cAh1, cAl0, cAl1, 0);
        __syncthreads();

        if (t2 + 2 < 64) {
            stageW(t2 + 2, 0);
            LOADA(cAh0, cAh1, cAl0, cAl1, t2 + 2);
        }
        MFMA_TILE(nAh0, nAh1, nAl0, nAl1, 1);
        if (((t2 + 1) & 7) == 7) epilogue(t2 + 1);
        __syncthreads();
    }
#undef LOADA
#undef MFMA_TILE

    #pragma unroll
    for (int r = 0; r < 16; ++r) {
        unsigned long long key =
            ((unsigned long long)f2key(bv[r]) << 32) | bi[r];
        unsigned sk = f2key(sv[r]);
        #pragma unroll
        for (int m = 1; m < 32; m <<= 1) {
            unsigned long long ko = __shfl_xor(key, m, 64);
            unsigned sko = __shfl_xor(sk, m, 64);
            unsigned long long loser = key < ko ? ko : key;
            sk = min(min(sk, sko), (unsigned)(loser >> 32));
            key = key < ko ? key : ko;
        }
        if (l31 == 0) {
            const int grow = r0 + wid * 32 + (r & 3) + 8 * (r >> 2) + 4 * h;
            unsigned long long old = atomicMin(&keys[grow], key);
            if (old != ~0ull) {
                unsigned long long loser = old < key ? key : old;
                atomicMin(&keys2[grow], (unsigned)(loser >> 32));
            }
            atomicMin(&keys2[grow], sk);
        }
    }
}

// ---------------- flag near-ties ----------------
extern "C" __global__ void flag_kernel(unsigned long long* __restrict__ keys,
                                       const unsigned* __restrict__ keys2,
                                       int* __restrict__ list, int* __restrict__ count) {
    const int row = blockIdx.x * 256 + threadIdx.x;
    unsigned long long k = keys[row];
    float b = key2f((unsigned)(k >> 32));
    float s = key2f(keys2[row]);
    if (s - b < EPS_GAP) {
        int p = atomicAdd(count, 1);
        list[p] = row;
        keys[row] = ~0ull;   // rerank rebuilds from scratch
    }
}

// ---------------- exact f32 rerank (code-resident, read-before-atomic) -----
extern "C" __global__ void __launch_bounds__(256)
rerank_kernel(const float* __restrict__ lat,
              const float* __restrict__ cbk,
              const float* __restrict__ wnorm,
              const int* __restrict__ list,
              const int* __restrict__ count,
              unsigned long long* __restrict__ keys) {
    const int w = threadIdx.x >> 6, lane = threadIdx.x & 63;
    const int c0 = blockIdx.x * 16 + w * 4;
    float4 wv0 = *(const float4*)&cbk[(size_t)(c0 + 0) * C_DIM + lane * 4];
    float4 wv1 = *(const float4*)&cbk[(size_t)(c0 + 1) * C_DIM + lane * 4];
    float4 wv2 = *(const float4*)&cbk[(size_t)(c0 + 2) * C_DIM + lane * 4];
    float4 wv3 = *(const float4*)&cbk[(size_t)(c0 + 3) * C_DIM + lane * 4];
    const float wn0 = wnorm[c0 + 0], wn1 = wnorm[c0 + 1];
    const float wn2 = wnorm[c0 + 2], wn3 = wnorm[c0 + 3];
    const int n = *count;

    auto dot4 = [&](const float4& x, const float4& v) {
        float d = x.x * v.x;
        d = fmaf(x.y, v.y, d);
        d = fmaf(x.z, v.z, d);
        return fmaf(x.w, v.w, d);
    };
    auto best4 = [&](float a0, float a1, float a2, float a3) {
        unsigned long long k0 = ((unsigned long long)f2key(fmaf(-2.0f, a0, wn0)) << 32) | (unsigned)(c0 + 0);
        unsigned long long k1 = ((unsigned long long)f2key(fmaf(-2.0f, a1, wn1)) << 32) | (unsigned)(c0 + 1);
        unsigned long long k2 = ((unsigned long long)f2key(fmaf(-2.0f, a2, wn2)) << 32) | (unsigned)(c0 + 2);
        unsigned long long k3 = ((unsigned long long)f2key(fmaf(-2.0f, a3, wn3)) << 32) | (unsigned)(c0 + 3);
        unsigned long long b01 = k0 < k1 ? k0 : k1;
        unsigned long long b23 = k2 < k3 ? k2 : k3;
        return b01 < b23 ? b01 : b23;
    };

    int i = 0;
    for (; i + 2 <= n; i += 2) {
        const int r0 = list[i], r1 = list[i + 1];
        float4 x0 = *(const float4*)&lat[(size_t)r0 * C_DIM + lane * 4];
        float4 x1 = *(const float4*)&lat[(size_t)r1 * C_DIM + lane * 4];
        float d00 = dot4(x0, wv0), d01 = dot4(x0, wv1), d02 = dot4(x0, wv2), d03 = dot4(x0, wv3);
        float d10 = dot4(x1, wv0), d11 = dot4(x1, wv1), d12 = dot4(x1, wv2), d13 = dot4(x1, wv3);
        #pragma unroll
        for (int m = 1; m < 64; m <<= 1) {
            d00 += __shfl_xor(d00, m, 64); d01 += __shfl_xor(d01, m, 64);
            d02 += __shfl_xor(d02, m, 64); d03 += __shfl_xor(d03, m, 64);
            d10 += __shfl_xor(d10, m, 64); d11 += __shfl_xor(d11, m, 64);
            d12 += __shfl_xor(d12, m, 64); d13 += __shfl_xor(d13, m, 64);
        }
        if (lane == 0) {
            unsigned long long b0 = best4(d00, d01, d02, d03);
            unsigned long long b1 = best4(d10, d11, d12, d13);
            if (b0 < keys[r0]) atomicMin(&keys[r0], b0);
            if (b1 < keys[r1]) atomicMin(&keys[r1], b1);
        }
    }
    if (i < n) {
        const int r0 = list[i];
        float4 x0 = *(const float4*)&lat[(size_t)r0 * C_DIM + lane * 4];
        float d00 = dot4(x0, wv0), d01 = dot4(x0, wv1), d02 = dot4(x0, wv2), d03 = dot4(x0, wv3);
        #pragma unroll
        for (int m = 1; m < 64; m <<= 1) {
            d00 += __shfl_xor(d00, m, 64); d01 += __shfl_xor(d01, m, 64);
            d02 += __shfl_xor(d02, m, 64); d03 += __shfl_xor(d03, m, 64);
        }
        if (lane == 0) {
            unsigned long long b0 = best4(d00, d01, d02, d03);
            if (b0 < keys[r0]) atomicMin(&keys[r0], b0);
        }
    }
}

// ---------------- finalize: 8 rows/block (2048 blocks) ----------------
extern "C" __global__ void finalize_kernel(const float* __restrict__ lat,
                                           const float* __restrict__ cbk,
                                           const float* __restrict__ noise,
                                           const unsigned long long* __restrict__ keys,
                                           float* __restrict__ out,
                                           float* __restrict__ lpart) {
    const int g = threadIdx.x >> 5;
    const int l = threadIdx.x & 31;
    const int row = blockIdx.x * 8 + g;
    const unsigned long long p = keys[row];
    const int id = (int)(unsigned)(p & 0xFFFFFFFFull);
    const int off = (int)rintf(noise[row] * 0.5f);
    int idn = id + off;
    idn = idn < 0 ? 0 : (idn > K_CODES - 1 ? K_CODES - 1 : idn);
    const float4* latp = (const float4*)&lat[(size_t)row * C_DIM];
    const float4* qdp  = (const float4*)&cbk[(size_t)id  * C_DIM];
    const float4* qnp  = (const float4*)&cbk[(size_t)idn * C_DIM];
    float4* stp = (float4*)&out[(size_t)row * C_DIM];
    float t = 0.0f;
    #pragma unroll
    for (int j = 0; j < 2; ++j) {
        const int e = l + j * 32;
        float4 x  = latp[e];
        float4 qd = qdp[e];
        float4 qn = qnp[e];
        float4 st = {x.x + (qn.x - x.x), x.y + (qn.y - x.y),
                     x.z + (qn.z - x.z), x.w + (qn.w - x.w)};
        stp[e] = st;
        float d1, d2;
        d1 = x.x - qd.x; d2 = qn.x - x.x; t += 0.25f * d1 * d1 + d2 * d2;
        d1 = x.y - qd.y; d2 = qn.y - x.y; t += 0.25f * d1 * d1 + d2 * d2;
        d1 = x.z - qd.z; d2 = qn.z - x.z; t += 0.25f * d1 * d1 + d2 * d2;
        d1 = x.w - qd.w; d2 = qn.w - x.w; t += 0.25f * d1 * d1 + d2 * d2;
    }
    t *= (1.0f / 4194304.0f);
    #pragma unroll
    for (int m = 1; m < 32; m <<= 1) t += __shfl_xor(t, m, 64);
    __shared__ float red[8];
    if (l == 0) {
        red[g] = t;
        out[(size_t)N_ROWS * C_DIM + 1 + row] = (float)idn;
    }
    __syncthreads();
    if (threadIdx.x == 0) {
        float s = red[0] + red[1] + red[2] + red[3] + red[4] + red[5] + red[6] + red[7];
        atomicAdd(&lpart[blockIdx.x & 1023], s);
    }
}

extern "C" __global__ void loss_reduce_kernel(const float* __restrict__ lpart,
                                              float* __restrict__ out) {
    const int t = threadIdx.x;
    float s = lpart[t] + lpart[t + 256] + lpart[t + 512] + lpart[t + 768];
    #pragma unroll
    for (int m = 32; m; m >>= 1) s += __shfl_xor(s, m, 64);
    __shared__ float red[4];
    if ((t & 63) == 0) red[t >> 6] = s;
    __syncthreads();
    if (t == 0) out[(size_t)N_ROWS * C_DIM] = red[0] + red[1] + red[2] + red[3];
}

extern "C" void kernel_launch(void* const* d_in, const int* in_sizes, int n_in,
                              void* d_out, int out_size, void* d_ws, size_t ws_size,
                              hipStream_t stream) {
    const float* lat   = (const float*)d_in[0];
    const float* cbk   = (const float*)d_in[1];
    const float* noise = (const float*)d_in[2];
    float* out = (float*)d_out;

    char* ws = (char*)d_ws;
    unsigned short* xh = (unsigned short*)(ws);                      //  8 MB (frag-major)
    unsigned short* xl = (unsigned short*)(ws + 8388608);            //  8 MB (frag-major)
    unsigned short* wh = (unsigned short*)(ws + 16777216);           //  4 MB (row-major)
    unsigned short* wl = (unsigned short*)(ws + 20971520);           //  4 MB (row-major)
    float* wnorm       = (float*)(ws + 25165824);                    // 32 KB
    unsigned long long* keys = (unsigned long long*)(ws + 25198592); // 128 KB  \ one
    unsigned* keys2    = (unsigned*)(ws + 25329664);                 // 64 KB   / 0xFF memset
    int* list          = (int*)(ws + 25395200);                      // 64 KB
    float* lpart       = (float*)(ws + 25460736);                    // 4 KB    \ one
    int* count         = (int*)(ws + 25464832);                      // 4 B     / 0 memset

    hipMemsetAsync(keys, 0xFF, 192 * 1024, stream);                  // keys + keys2
    hipMemsetAsync(lpart, 0, 4096 + 4, stream);                      // lpart + count

    prep_all_kernel<<<3072, 256, 0, stream>>>(lat, cbk, xh, xl, wh, wl, wnorm);
    pass1_kernel<<<1024, 256, 0, stream>>>(xh, xl, wh, wl, wnorm, keys, keys2);
    flag_kernel <<<N_ROWS / 256, 256, 0, stream>>>(keys, keys2, list, count);
    rerank_kernel<<<512, 256, 0, stream>>>(lat, cbk, wnorm, list, count, keys);
    finalize_kernel<<<N_ROWS / 8, 256, 0, stream>>>(lat, cbk, noise, keys, out, lpart);
    loss_reduce_kernel<<<1, 256, 0, stream>>>(lpart, out);
}